// Round 14
// baseline (111.959 us; speedup 1.0000x reference)
//
#include <hip/hip_runtime.h>

// Problem constants (fixed by the reference file)
#define NN 8192
#define PPU 33550336u              // P = N(N-1)/2
static const long long PP = (long long)PPU;

typedef float __attribute__((ext_vector_type(4))) fx4;      // nontemporal-store-able
typedef float __attribute__((ext_vector_type(2))) fx2;

// skewed LDS index for M float4 rows
#define MSI(j) ((j) + ((j) >> 3))

// ---------------------------------------------------------------------------
// K1: blocks 0..255  -> ab projections (8 threads cooperate per node)
//     blocks 256..8446 -> zero yt (16 KB contiguous per block)
// [byte-identical to the R10 champion]
// ---------------------------------------------------------------------------
__global__ __launch_bounds__(256) void ab_zero_kernel(
    const float* __restrict__ nodes,   // [8192][256]
    const float* __restrict__ W_enc,   // [256][256]
    const float* __restrict__ b_enc,   // [256]
    const float* __restrict__ W_cls,   // [512][2]
    const float* __restrict__ b_cls,   // [2]
    float2* __restrict__ Axy,          // ws: [8192]
    float2* __restrict__ Bzw,          // ws: [8192]
    float*  __restrict__ yt)           // out: [P]
{
    const int tid = threadIdx.x;
    const int bid = blockIdx.x;

    if (bid >= 256) {
        fx4* base = (fx4*)yt + (unsigned)(bid - 256) * 1024u + (unsigned)tid;
        fx4 z = {0.f, 0.f, 0.f, 0.f};
        __builtin_nontemporal_store(z, base + 0 * 256);
        __builtin_nontemporal_store(z, base + 1 * 256);
        __builtin_nontemporal_store(z, base + 2 * 256);
        __builtin_nontemporal_store(z, base + 3 * 256);
        return;
    }

    __shared__ float  wc[1024];        // W_cls [512][2]
    __shared__ float4 msv[288];        // skewed M rows
    __shared__ float  offs[4];

    for (int i = tid; i < 1024; i += 256) wc[i] = W_cls[i];
    __syncthreads();

    {
        const float4* wr  = (const float4*)(W_enc + tid * 256);
        const float4* wa4 = (const float4*)wc;          // A half
        const float4* wb4 = (const float4*)(wc + 512);  // B half
        float a0 = 0.f, a1 = 0.f, a2 = 0.f, a3 = 0.f;
        #pragma unroll 8
        for (int i = 0; i < 64; ++i) {
            const float4 v   = wr[i];
            const float4 A01 = wa4[2*i],   A23 = wa4[2*i+1];
            const float4 B01 = wb4[2*i],   B23 = wb4[2*i+1];
            a0 += v.x*A01.x + v.y*A01.z + v.z*A23.x + v.w*A23.z;
            a1 += v.x*A01.y + v.y*A01.w + v.z*A23.y + v.w*A23.w;
            a2 += v.x*B01.x + v.y*B01.z + v.z*B23.x + v.w*B23.z;
            a3 += v.x*B01.y + v.y*B01.w + v.z*B23.y + v.w*B23.w;
        }
        msv[MSI(tid)] = make_float4(a0, a1, a2, a3);
    }
    if (tid < 4) {
        const int c = tid & 1, base = (tid < 2) ? 0 : 256;
        float o = 0.f;
        for (int j = 0; j < 256; ++j) o += b_enc[j] * wc[(base + j) * 2 + c];
        if (tid < 2) o += b_cls[tid];      // fold b_cls into the A half
        offs[tid] = o;
    }
    __syncthreads();

    const int gid  = bid * 256 + tid;
    const int n    = gid >> 3;             // 0..8191
    const int part = gid & 7;
    float a0 = 0.f, a1 = 0.f, a2 = 0.f, a3 = 0.f;
    const float4* row = (const float4*)(nodes + (long long)n * 256 + part * 32);
    #pragma unroll
    for (int i = 0; i < 8; ++i) {
        const float4 v = row[i];
        const int j = part * 32 + i * 4;
        const float4 m0 = msv[MSI(j+0)];
        const float4 m1 = msv[MSI(j+1)];
        const float4 m2 = msv[MSI(j+2)];
        const float4 m3 = msv[MSI(j+3)];
        a0 += v.x*m0.x + v.y*m1.x + v.z*m2.x + v.w*m3.x;
        a1 += v.x*m0.y + v.y*m1.y + v.z*m2.y + v.w*m3.y;
        a2 += v.x*m0.z + v.y*m1.z + v.z*m2.z + v.w*m3.z;
        a3 += v.x*m0.w + v.y*m1.w + v.z*m2.w + v.w*m3.w;
    }
    #pragma unroll
    for (int d = 1; d < 8; d <<= 1) {
        a0 += __shfl_xor(a0, d);
        a1 += __shfl_xor(a1, d);
        a2 += __shfl_xor(a2, d);
        a3 += __shfl_xor(a3, d);
    }
    if (part == 0) {
        Axy[n] = make_float2(a0 + offs[0], a1 + offs[1]);
        Bzw[n] = make_float2(a2 + offs[2], a3 + offs[3]);
    }
}

// ---------------------------------------------------------------------------
// K2: row-wise one-shot fill.  grid (16, 8191): by = row s, bx = 512-pair
// chunk within the row.  No sqrt, no fixups; Axy[s] is wave-uniform (scalar
// load); Bzw loads are lane-contiguous; 2 fx2 NT stores per thread.
// Minimal wave lifetime (~8 VALU + 2 loads + 2 stores).  Blocks past the
// row end exit in 2 instructions.  Edge scatter piggybacks on (bx=0, s<256).
// ---------------------------------------------------------------------------
__global__ __launch_bounds__(256) void fill_row_kernel(
    const float2* __restrict__ Axy,    // [8192]
    const float2* __restrict__ Bzw,    // [8192]
    const int*    __restrict__ edges,  // [2][E]
    float* __restrict__ y,             // [P][2]
    float* __restrict__ yt,            // [P]
    int E)
{
    const unsigned s    = blockIdx.y;            // row 0..8190
    const unsigned off0 = blockIdx.x * 512u;     // chunk offset within row
    const unsigned L    = 8191u - s;             // row length
    if (off0 >= L) return;                       // early-exit block

    const int tid = threadIdx.x;

    // edge scatter piggyback: (bx==0, s<256) x 256 threads covers E=65536
    if (blockIdx.x == 0 && s < 256u) {
        const unsigned ge = s * 256u + (unsigned)tid;
        if (ge < (unsigned)E) {
            const int u = edges[ge], v = edges[E + ge];
            if (u < v) {
                const unsigned idx = (((unsigned)u * (16383u - (unsigned)u)) >> 1)
                                   + (unsigned)(v - u - 1);
                yt[idx] = 1.0f;
            }
        }
    }

    const unsigned rs = (s * (16383u - s)) >> 1;     // row start pair index
    const float2 a = Axy[s];                          // uniform -> scalar load
    const unsigned o1 = off0 + (unsigned)tid;
    const unsigned o2 = o1 + 256u;
    const bool v1 = o1 < L;
    const bool v2 = o2 < L;

    float2 b1, b2;
    if (v1) b1 = Bzw[s + 1u + o1];
    if (v2) b2 = Bzw[s + 1u + o2];

    if (v1) {
        fx2 w = {a.x + b1.x, a.y + b1.y};
        __builtin_nontemporal_store(w, (fx2*)(y + 2u * (rs + o1)));
    }
    if (v2) {
        fx2 w = {a.x + b2.x, a.y + b2.y};
        __builtin_nontemporal_store(w, (fx2*)(y + 2u * (rs + o2)));
    }
}

extern "C" void kernel_launch(void* const* d_in, const int* in_sizes, int n_in,
                              void* d_out, int out_size, void* d_ws, size_t ws_size,
                              hipStream_t stream) {
    const float* nodes = (const float*)d_in[0];
    const int*   edges = (const int*)d_in[1];
    const float* W_enc = (const float*)d_in[2];
    const float* b_enc = (const float*)d_in[3];
    const float* W_cls = (const float*)d_in[4];
    const float* b_cls = (const float*)d_in[5];
    const int E = in_sizes[1] / 2;

    float2* Axy = (float2*)d_ws;                  // 8192 float2
    float2* Bzw = Axy + 8192;                     // 8192 float2

    float* y  = (float*)d_out;                    // [P][2]
    float* yt = (float*)d_out + 2 * PP;           // [P]

    // K1: 256 ab blocks + 8191 zero blocks (P floats = 8191*1024 fx4 exactly)
    ab_zero_kernel<<<256 + 8191, 256, 0, stream>>>(
        nodes, W_enc, b_enc, W_cls, b_cls, Axy, Bzw, yt);

    // K2: rows 0..8190, up to 16 chunks of 512 pairs each
    fill_row_kernel<<<dim3(16, 8191), 256, 0, stream>>>(
        Axy, Bzw, edges, y, yt, E);
}

// Round 15
// 93.234 us; speedup vs baseline: 1.2008x; 1.2008x over previous
//
#include <hip/hip_runtime.h>

// Problem constants (fixed by the reference file)
#define NN 8192
#define PPU 33550336u              // P = N(N-1)/2
static const long long PP = (long long)PPU;

typedef float __attribute__((ext_vector_type(4))) fx4;      // nontemporal-store-able

// skewed LDS index for M float4 rows
#define MSI(j) ((j) + ((j) >> 3))

// ---------------------------------------------------------------------------
// K1: blocks 0..255  -> ab projections (8 threads cooperate per node)
//     blocks 256..8446 -> zero yt (16 KB contiguous per block)
// [byte-identical to the R10 champion]
// ---------------------------------------------------------------------------
__global__ __launch_bounds__(256) void ab_zero_kernel(
    const float* __restrict__ nodes,   // [8192][256]
    const float* __restrict__ W_enc,   // [256][256]
    const float* __restrict__ b_enc,   // [256]
    const float* __restrict__ W_cls,   // [512][2]
    const float* __restrict__ b_cls,   // [2]
    float2* __restrict__ Axy,          // ws: [8192]
    float2* __restrict__ Bzw,          // ws: [8192]
    float*  __restrict__ yt)           // out: [P]
{
    const int tid = threadIdx.x;
    const int bid = blockIdx.x;

    if (bid >= 256) {
        fx4* base = (fx4*)yt + (unsigned)(bid - 256) * 1024u + (unsigned)tid;
        fx4 z = {0.f, 0.f, 0.f, 0.f};
        __builtin_nontemporal_store(z, base + 0 * 256);
        __builtin_nontemporal_store(z, base + 1 * 256);
        __builtin_nontemporal_store(z, base + 2 * 256);
        __builtin_nontemporal_store(z, base + 3 * 256);
        return;
    }

    __shared__ float  wc[1024];        // W_cls [512][2]
    __shared__ float4 msv[288];        // skewed M rows
    __shared__ float  offs[4];

    for (int i = tid; i < 1024; i += 256) wc[i] = W_cls[i];
    __syncthreads();

    {
        const float4* wr  = (const float4*)(W_enc + tid * 256);
        const float4* wa4 = (const float4*)wc;          // A half
        const float4* wb4 = (const float4*)(wc + 512);  // B half
        float a0 = 0.f, a1 = 0.f, a2 = 0.f, a3 = 0.f;
        #pragma unroll 8
        for (int i = 0; i < 64; ++i) {
            const float4 v   = wr[i];
            const float4 A01 = wa4[2*i],   A23 = wa4[2*i+1];
            const float4 B01 = wb4[2*i],   B23 = wb4[2*i+1];
            a0 += v.x*A01.x + v.y*A01.z + v.z*A23.x + v.w*A23.z;
            a1 += v.x*A01.y + v.y*A01.w + v.z*A23.y + v.w*A23.w;
            a2 += v.x*B01.x + v.y*B01.z + v.z*B23.x + v.w*B23.z;
            a3 += v.x*B01.y + v.y*B01.w + v.z*B23.y + v.w*B23.w;
        }
        msv[MSI(tid)] = make_float4(a0, a1, a2, a3);
    }
    if (tid < 4) {
        const int c = tid & 1, base = (tid < 2) ? 0 : 256;
        float o = 0.f;
        for (int j = 0; j < 256; ++j) o += b_enc[j] * wc[(base + j) * 2 + c];
        if (tid < 2) o += b_cls[tid];      // fold b_cls into the A half
        offs[tid] = o;
    }
    __syncthreads();

    const int gid  = bid * 256 + tid;
    const int n    = gid >> 3;             // 0..8191
    const int part = gid & 7;
    float a0 = 0.f, a1 = 0.f, a2 = 0.f, a3 = 0.f;
    const float4* row = (const float4*)(nodes + (long long)n * 256 + part * 32);
    #pragma unroll
    for (int i = 0; i < 8; ++i) {
        const float4 v = row[i];
        const int j = part * 32 + i * 4;
        const float4 m0 = msv[MSI(j+0)];
        const float4 m1 = msv[MSI(j+1)];
        const float4 m2 = msv[MSI(j+2)];
        const float4 m3 = msv[MSI(j+3)];
        a0 += v.x*m0.x + v.y*m1.x + v.z*m2.x + v.w*m3.x;
        a1 += v.x*m0.y + v.y*m1.y + v.z*m2.y + v.w*m3.y;
        a2 += v.x*m0.z + v.y*m1.z + v.z*m2.z + v.w*m3.z;
        a3 += v.x*m0.w + v.y*m1.w + v.z*m2.w + v.w*m3.w;
    }
    #pragma unroll
    for (int d = 1; d < 8; d <<= 1) {
        a0 += __shfl_xor(a0, d);
        a1 += __shfl_xor(a1, d);
        a2 += __shfl_xor(a2, d);
        a3 += __shfl_xor(a3, d);
    }
    if (part == 0) {
        Axy[n] = make_float2(a0 + offs[0], a1 + offs[1]);
        Bzw[n] = make_float2(a2 + offs[2], a3 + offs[3]);
    }
}

// ---------------------------------------------------------------------------
// K2: fill y (R10's exact per-thread body) with 64-thread (1-wave) blocks:
// CU slots recycle at wave granularity instead of 4-wave block granularity.
// 262,112 blocks x 64 threads = NSEG segments exactly.
// Edge scatter on first 1024 blocks (g < E = 65536).
// ---------------------------------------------------------------------------
__global__ __launch_bounds__(64) void fill_edge_kernel(
    const float2* __restrict__ Axy,    // [8192]
    const float2* __restrict__ Bzw,    // [8192]
    const int*    __restrict__ edges,  // [2][E]
    float* __restrict__ y,             // [P][2]
    float* __restrict__ yt,            // [P]
    int E)
{
    const unsigned g = blockIdx.x * 64u + threadIdx.x;

    // edge scatter (first E threads only; E = 65536 = first 1024 blocks)
    if (g < (unsigned)E) {
        const int u = edges[g];
        const int v = edges[E + g];
        if (u < v) {
            const unsigned idx = (((unsigned)u * (16383u - (unsigned)u)) >> 1)
                               + (unsigned)(v - u - 1);
            yt[idx] = 1.0f;
        }
    }

    const unsigned p0 = 2u * g;                       // < 2^26

    // invert p0 -> (s,t): s = floor((M - sqrt(M^2 - 8 p0))/2), M = 2N-1
    const unsigned M    = 16383u;
    const unsigned disc = M * M - 8u * p0;            // exact in uint32
    const float sq = sqrtf((float)disc);
    int s = (int)(((float)M - sq) * 0.5f);
    s = s < 0 ? 0 : (s > NN - 2 ? NN - 2 : s);
    unsigned rs = ((unsigned)s * (M - (unsigned)s)) >> 1;
    while (p0 < rs)                           { --s; rs -= (unsigned)(NN - 1 - s); }
    while (p0 >= rs + (unsigned)(NN - 1 - s)) { rs += (unsigned)(NN - 1 - s); ++s; }
    int t = (int)(p0 - rs) + s + 1;

    float2 a  = Axy[s];
    float2 b0 = Bzw[t];
    const float o0 = a.x + b0.x, o1 = a.y + b0.y;
    if (++t == NN) { ++s; t = s + 1; a = Axy[s]; }    // row crossing (rare)
    float2 b1 = Bzw[t];
    fx4 v = {o0, o1, a.x + b1.x, a.y + b1.y};
    __builtin_nontemporal_store(v, (fx4*)(y + 4u * g));
}

extern "C" void kernel_launch(void* const* d_in, const int* in_sizes, int n_in,
                              void* d_out, int out_size, void* d_ws, size_t ws_size,
                              hipStream_t stream) {
    const float* nodes = (const float*)d_in[0];
    const int*   edges = (const int*)d_in[1];
    const float* W_enc = (const float*)d_in[2];
    const float* b_enc = (const float*)d_in[3];
    const float* W_cls = (const float*)d_in[4];
    const float* b_cls = (const float*)d_in[5];
    const int E = in_sizes[1] / 2;

    float2* Axy = (float2*)d_ws;                  // 8192 float2
    float2* Bzw = Axy + 8192;                     // 8192 float2

    float* y  = (float*)d_out;                    // [P][2]
    float* yt = (float*)d_out + 2 * PP;           // [P]

    // K1: 256 ab blocks + 8191 zero blocks (P floats = 8191*1024 fx4 exactly)
    ab_zero_kernel<<<256 + 8191, 256, 0, stream>>>(
        nodes, W_enc, b_enc, W_cls, b_cls, Axy, Bzw, yt);

    // K2: NSEG/64 = 262,112 one-wave blocks
    fill_edge_kernel<<<262112, 64, 0, stream>>>(Axy, Bzw, edges, y, yt, E);
}

// Round 16
// 78.574 us; speedup vs baseline: 1.4249x; 1.1866x over previous
//
#include <hip/hip_runtime.h>

// Problem constants (fixed by the reference file)
#define NN 8192
#define PPU 33550336u              // P = N(N-1)/2
static const long long PP = (long long)PPU;

typedef float __attribute__((ext_vector_type(4))) fx4;      // nontemporal-store-able

// skewed LDS index for M float4 rows (projection-phase conflict damping)
#define MSI(j) ((j) + ((j) >> 3))

// ---------------------------------------------------------------------------
// K1: blocks 0..255  -> ab projections (8 threads cooperate per node)
//     blocks 256..8446 -> zero yt (16 KB contiguous per block)
// Disjoint outputs (ws vs yt) -> safe in one launch.   [R10 champion]
// ---------------------------------------------------------------------------
__global__ __launch_bounds__(256) void ab_zero_kernel(
    const float* __restrict__ nodes,   // [8192][256]
    const float* __restrict__ W_enc,   // [256][256]
    const float* __restrict__ b_enc,   // [256]
    const float* __restrict__ W_cls,   // [512][2]
    const float* __restrict__ b_cls,   // [2]
    float2* __restrict__ Axy,          // ws: [8192]
    float2* __restrict__ Bzw,          // ws: [8192]
    float*  __restrict__ yt)           // out: [P]
{
    const int tid = threadIdx.x;
    const int bid = blockIdx.x;

    if (bid >= 256) {
        // ---- zero yt: block covers 16 KB contiguous ----
        fx4* base = (fx4*)yt + (unsigned)(bid - 256) * 1024u + (unsigned)tid;
        fx4 z = {0.f, 0.f, 0.f, 0.f};
        __builtin_nontemporal_store(z, base + 0 * 256);
        __builtin_nontemporal_store(z, base + 1 * 256);
        __builtin_nontemporal_store(z, base + 2 * 256);
        __builtin_nontemporal_store(z, base + 3 * 256);
        return;
    }

    // ---- ab path ----
    __shared__ float  wc[1024];        // W_cls [512][2]
    __shared__ float4 msv[288];        // skewed M rows
    __shared__ float  offs[4];

    for (int i = tid; i < 1024; i += 256) wc[i] = W_cls[i];
    __syncthreads();

    // M row `tid` via vectorized (b128, broadcast) wc reads
    {
        const float4* wr  = (const float4*)(W_enc + tid * 256);
        const float4* wa4 = (const float4*)wc;          // A half: j-pairs
        const float4* wb4 = (const float4*)(wc + 512);  // B half: j-pairs
        float a0 = 0.f, a1 = 0.f, a2 = 0.f, a3 = 0.f;
        #pragma unroll 8
        for (int i = 0; i < 64; ++i) {
            const float4 v   = wr[i];
            const float4 A01 = wa4[2*i],   A23 = wa4[2*i+1];
            const float4 B01 = wb4[2*i],   B23 = wb4[2*i+1];
            a0 += v.x*A01.x + v.y*A01.z + v.z*A23.x + v.w*A23.z;
            a1 += v.x*A01.y + v.y*A01.w + v.z*A23.y + v.w*A23.w;
            a2 += v.x*B01.x + v.y*B01.z + v.z*B23.x + v.w*B23.z;
            a3 += v.x*B01.y + v.y*B01.w + v.z*B23.y + v.w*B23.w;
        }
        msv[MSI(tid)] = make_float4(a0, a1, a2, a3);
    }
    if (tid < 4) {
        const int c = tid & 1, base = (tid < 2) ? 0 : 256;
        float o = 0.f;
        for (int j = 0; j < 256; ++j) o += b_enc[j] * wc[(base + j) * 2 + c];
        if (tid < 2) o += b_cls[tid];      // fold b_cls into the A half
        offs[tid] = o;
    }
    __syncthreads();

    // 8 threads per node; lane part handles dims [32*part, 32*part+32)
    const int gid  = bid * 256 + tid;
    const int n    = gid >> 3;             // 0..8191
    const int part = gid & 7;
    float a0 = 0.f, a1 = 0.f, a2 = 0.f, a3 = 0.f;
    const float4* row = (const float4*)(nodes + (long long)n * 256 + part * 32);
    #pragma unroll
    for (int i = 0; i < 8; ++i) {
        const float4 v = row[i];
        const int j = part * 32 + i * 4;
        const float4 m0 = msv[MSI(j+0)];
        const float4 m1 = msv[MSI(j+1)];
        const float4 m2 = msv[MSI(j+2)];
        const float4 m3 = msv[MSI(j+3)];
        a0 += v.x*m0.x + v.y*m1.x + v.z*m2.x + v.w*m3.x;
        a1 += v.x*m0.y + v.y*m1.y + v.z*m2.y + v.w*m3.y;
        a2 += v.x*m0.z + v.y*m1.z + v.z*m2.z + v.w*m3.z;
        a3 += v.x*m0.w + v.y*m1.w + v.z*m2.w + v.w*m3.w;
    }
    #pragma unroll
    for (int d = 1; d < 8; d <<= 1) {
        a0 += __shfl_xor(a0, d);
        a1 += __shfl_xor(a1, d);
        a2 += __shfl_xor(a2, d);
        a3 += __shfl_xor(a3, d);
    }
    if (part == 0) {
        Axy[n] = make_float2(a0 + offs[0], a1 + offs[1]);
        Bzw[n] = make_float2(a2 + offs[2], a3 + offs[3]);
    }
}

// ---------------------------------------------------------------------------
// K2: fill y (one-shot 1-store waves; SoA Axy/Bzw) + edge scatter on first
// 256 blocks (gid < E; E = 65536 = 256*256).  Runs after K1, so yt is zeroed.
// ---------------------------------------------------------------------------
__global__ __launch_bounds__(256) void fill_edge_kernel(
    const float2* __restrict__ Axy,    // [8192]
    const float2* __restrict__ Bzw,    // [8192]
    const int*    __restrict__ edges,  // [2][E]
    float* __restrict__ y,             // [P][2]
    float* __restrict__ yt,            // [P]
    int E)
{
    const unsigned g = blockIdx.x * 256u + threadIdx.x;

    // edge scatter (first E threads only)
    if (g < (unsigned)E) {
        const int u = edges[g];
        const int v = edges[E + g];
        if (u < v) {
            const unsigned idx = (((unsigned)u * (16383u - (unsigned)u)) >> 1)
                               + (unsigned)(v - u - 1);
            yt[idx] = 1.0f;
        }
    }

    const unsigned p0 = 2u * g;                       // < 2^26

    // invert p0 -> (s,t): s = floor((M - sqrt(M^2 - 8 p0))/2), M = 2N-1
    const unsigned M    = 16383u;
    const unsigned disc = M * M - 8u * p0;            // exact in uint32
    const float sq = sqrtf((float)disc);
    int s = (int)(((float)M - sq) * 0.5f);
    s = s < 0 ? 0 : (s > NN - 2 ? NN - 2 : s);
    unsigned rs = ((unsigned)s * (M - (unsigned)s)) >> 1;
    while (p0 < rs)                           { --s; rs -= (unsigned)(NN - 1 - s); }
    while (p0 >= rs + (unsigned)(NN - 1 - s)) { rs += (unsigned)(NN - 1 - s); ++s; }
    int t = (int)(p0 - rs) + s + 1;

    float2 a  = Axy[s];
    float2 b0 = Bzw[t];
    const float o0 = a.x + b0.x, o1 = a.y + b0.y;
    if (++t == NN) { ++s; t = s + 1; a = Axy[s]; }    // row crossing (rare)
    float2 b1 = Bzw[t];
    fx4 v = {o0, o1, a.x + b1.x, a.y + b1.y};
    __builtin_nontemporal_store(v, (fx4*)(y + 4u * g));
}

extern "C" void kernel_launch(void* const* d_in, const int* in_sizes, int n_in,
                              void* d_out, int out_size, void* d_ws, size_t ws_size,
                              hipStream_t stream) {
    const float* nodes = (const float*)d_in[0];
    const int*   edges = (const int*)d_in[1];
    const float* W_enc = (const float*)d_in[2];
    const float* b_enc = (const float*)d_in[3];
    const float* W_cls = (const float*)d_in[4];
    const float* b_cls = (const float*)d_in[5];
    const int E = in_sizes[1] / 2;

    float2* Axy = (float2*)d_ws;                  // 8192 float2
    float2* Bzw = Axy + 8192;                     // 8192 float2

    float* y  = (float*)d_out;                    // [P][2]
    float* yt = (float*)d_out + 2 * PP;           // [P]

    // K1: 256 ab blocks + 8191 zero blocks (P floats = 8191*1024 fx4 exactly)
    ab_zero_kernel<<<256 + 8191, 256, 0, stream>>>(
        nodes, W_enc, b_enc, W_cls, b_cls, Axy, Bzw, yt);

    // K2: P/2 threads (= 65528 * 256 exactly); first 256 blocks also edges
    fill_edge_kernel<<<(int)(PPU / 512u), 256, 0, stream>>>(
        Axy, Bzw, edges, y, yt, E);
}